// Round 16
// baseline (288.521 us; speedup 1.0000x reference)
//
#include <hip/hip_runtime.h>
#include <math.h>

#define C_IN  32
#define O_OUT 32
#define HIMG  112
#define WIMG  112
#define HW    (HIMG * WIMG)
#define TS    8            // spatial tile 8x8
#define NT    14           // tiles per image dim
#define NCP   16           // c-pairs (2 channels per f16x2 reg)
#define XROW  12           // h2 per halo row (10 used) -> rows 16B-aligned
#define XPLANE (10 * XROW) // 120 h2 per c-pair plane
#define XTILE (NCP * XPLANE)          // 1920 h2 = 7680 B per (n,ti,tj)
#define NXT   (8 * NT * NT * XTILE)   // 12,042,240 B
#define WSLOT 12           // h2 per (o,cp) slot (9 used) -> 48B, b128-aligned
#define WSTRIDE 196        // h2 per o in ws (192 used +4 -> bank spread)
#define OBLK  16           // o per block (o-split 2)
#define NW    (O_OUT * NCP * WSLOT)   // 24576 B global scratch

typedef _Float16 h2 __attribute__((ext_vector_type(2)));

// R13 A/B: __builtin_elementwise_min/max scalarizes on gfx950 (ROCm 7.2);
// force v_pk_min/max_f16 via asm (~15% end-to-end).
static __device__ __forceinline__ h2 h2min(h2 a, h2 b) {
    h2 r; asm("v_pk_min_f16 %0, %1, %2" : "=v"(r) : "v"(a), "v"(b)); return r;
}
static __device__ __forceinline__ h2 h2max(h2 a, h2 b) {
    h2 r; asm("v_pk_max_f16 %0, %1, %2" : "=v"(r) : "v"(a), "v"(b)); return r;
}

static __device__ __forceinline__ h2 asH2(float f) {
    union { float f; h2 h; } u; u.f = f; return u.h;
}
static __device__ __forceinline__ float asF(h2 h) {
    union { h2 h; float f; } u; u.h = h; return u.f;
}

__global__ void prep_weights(const float* __restrict__ kern, h2* __restrict__ wp)
{
    int idx = blockIdx.x * 256 + threadIdx.x;     // 6144 total
    if (idx >= NW) return;
    int k  = idx % WSLOT;
    int cp = (idx / WSLOT) & (NCP - 1);
    int o  = idx / (WSLOT * NCP);
    float a = -INFINITY, b = -INFINITY;
    if (k < 9) {
        a = kern[(o * C_IN + 2 * cp    ) * 9 + k];
        b = kern[(o * C_IN + 2 * cp + 1) * 9 + k];
    }
    h2 v; v.x = (_Float16)a; v.y = (_Float16)b;
    wp[idx] = v;
}

// Pre-tile x: xt[n][ti][tj][cp][r(10)][col(12)] f16x2, halo + -inf baked in.
__global__ void pack_x(const float* __restrict__ x, h2* __restrict__ xt)
{
    int idx = blockIdx.x * 256 + threadIdx.x;
    if (idx >= NXT) return;
    int col = idx % XROW;
    int r   = (idx / XROW) % 10;
    int cp  = (idx / XPLANE) & (NCP - 1);
    int tj  = (idx / XTILE) % NT;
    int ti  = (idx / (XTILE * NT)) % NT;
    int n   = idx / (XTILE * NT * NT);
    int gi  = ti * TS + r - 1;
    int gj  = tj * TS + col - 1;
    float a = -INFINITY, b = -INFINITY;
    if (col < 10 && (unsigned)gi < (unsigned)HIMG && (unsigned)gj < (unsigned)WIMG) {
        const float* p = x + ((size_t)(n * C_IN + 2 * cp) * HIMG + gi) * WIMG + gj;
        a = p[0];
        b = p[HW];
    }
    h2 v; v.x = (_Float16)a; v.y = (_Float16)b;
    xt[idx] = v;
}

struct Tile {
    h2 xr[4][10];
    h2 w[9];
};

static __device__ __forceinline__ void load_tile(Tile& t, const h2* __restrict__ xp,
                                                 const h2* __restrict__ wq)
{
    #pragma unroll
    for (int q = 0; q < 4; ++q) {
        const h2* rp = xp + q * XROW;
        float4 a = *(const float4*)rp;         // ds_read_b128
        float4 b = *(const float4*)(rp + 4);   // ds_read_b128
        float2 c = *(const float2*)(rp + 8);   // ds_read_b64
        t.xr[q][0] = asH2(a.x); t.xr[q][1] = asH2(a.y);
        t.xr[q][2] = asH2(a.z); t.xr[q][3] = asH2(a.w);
        t.xr[q][4] = asH2(b.x); t.xr[q][5] = asH2(b.y);
        t.xr[q][6] = asH2(b.z); t.xr[q][7] = asH2(b.w);
        t.xr[q][8] = asH2(c.x); t.xr[q][9] = asH2(c.y);
    }
    float4 wa = *(const float4*)wq;
    float4 wb = *(const float4*)(wq + 4);
    float  wc = *(const float*)(wq + 8);
    t.w[0] = asH2(wa.x); t.w[1] = asH2(wa.y); t.w[2] = asH2(wa.z); t.w[3] = asH2(wa.w);
    t.w[4] = asH2(wb.x); t.w[5] = asH2(wb.y); t.w[6] = asH2(wb.z); t.w[7] = asH2(wb.w);
    t.w[8] = asH2(wc);
}

static __device__ __forceinline__ void compute_tile(const Tile& t, h2 acc[2][8])
{
    #pragma unroll
    for (int rr = 0; rr < 2; ++rr) {
        #pragma unroll
        for (int j = 0; j < 8; ++j) {
            h2 t0 = h2min(t.xr[rr    ][j    ], t.w[0]);
            h2 t1 = h2min(t.xr[rr    ][j + 1], t.w[1]);
            h2 t2 = h2min(t.xr[rr    ][j + 2], t.w[2]);
            h2 t3 = h2min(t.xr[rr + 1][j    ], t.w[3]);
            h2 t4 = h2min(t.xr[rr + 1][j + 1], t.w[4]);
            h2 t5 = h2min(t.xr[rr + 1][j + 2], t.w[5]);
            h2 t6 = h2min(t.xr[rr + 2][j    ], t.w[6]);
            h2 t7 = h2min(t.xr[rr + 2][j + 1], t.w[7]);
            h2 t8 = h2min(t.xr[rr + 2][j + 2], t.w[8]);
            h2 r0 = h2max(h2max(t0, t1), t2);
            h2 r1 = h2max(h2max(t3, t4), t5);
            h2 r2 = h2max(h2max(t6, t7), t8);
            acc[rr][j] = h2max(acc[rr][j], h2max(h2max(r0, r1), r2));
        }
    }
}

// A/B/C on the occupancy cap only: MW = min waves/EU (VGPR cap 128/85/64).
// All variants compute the full correct output. VGPR_Count per rocprof row
// is the remat-trap detector (R9: cap forced VGPR 32 -> remat -> null).
template<int MW, bool TILED>
__global__ __launch_bounds__(256, MW) void semiconv_tpl(
    const float* __restrict__ x, const h2* __restrict__ xt,
    const h2* __restrict__ wp, float* __restrict__ out)
{
    __shared__ h2 xs[NCP * XPLANE];      // 7680 B
    __shared__ h2 ws[OBLK * WSTRIDE];    // 12544 B (total 20224 B)

    const int tid = threadIdx.x;
    const int tj0 = blockIdx.x * TS;
    const int ti0 = blockIdx.y * TS;
    const int n   = blockIdx.z >> 1;
    const int o0  = (blockIdx.z & 1) * OBLK;

    #pragma unroll
    for (int i = 0; i < 3; ++i) {
        int chunk = i * 256 + tid;
        int oL    = chunk / 48;
        int rem   = chunk - oL * 48;
        float4 v  = *(const float4*)&wp[(size_t)((o0 + oL) * 48 + rem) * 4];
        *(float4*)&ws[oL * WSTRIDE + rem * 4] = v;
    }
    if constexpr (TILED) {
        const float4* xtp = (const float4*)(xt
            + (size_t)((n * NT + blockIdx.y) * NT + blockIdx.x) * XTILE);
        float4* xsp = (float4*)xs;
        xsp[tid] = xtp[tid];
        if (tid < 480 - 256) xsp[256 + tid] = xtp[256 + tid];
    } else {
        const float* xn = x + (size_t)n * (C_IN * HW);
        #pragma unroll 1
        for (int idx = tid; idx < NCP * XPLANE; idx += 256) {
            int cp  = idx / XPLANE;
            int rem = idx - cp * XPLANE;
            int r   = rem / XROW;
            int col = rem - r * XROW;
            int gi = ti0 - 1 + r, gj = tj0 - 1 + col;
            float a = -INFINITY, b = -INFINITY;
            if (col < 10 && (unsigned)gi < (unsigned)HIMG && (unsigned)gj < (unsigned)WIMG) {
                const float* p = xn + (size_t)(2 * cp) * HW + gi * WIMG + gj;
                a = p[0];
                b = p[HW];
            }
            h2 v; v.x = (_Float16)a; v.y = (_Float16)b;
            xs[idx] = v;
        }
    }
    __syncthreads();

    const int lane = tid & 63;
    const int wv   = tid >> 6;               // cp-quarter, 0..3
    const int oL   = lane & 15;              // o within block, 0..15
    const int prg  = lane >> 4;              // row-pair group, 0..3
    const int o    = o0 + oL;

    h2 ninf2; ninf2.x = (_Float16)(-INFINITY); ninf2.y = (_Float16)(-INFINITY);
    h2 acc[2][8];
    #pragma unroll
    for (int rr = 0; rr < 2; ++rr)
        #pragma unroll
        for (int j = 0; j < 8; ++j) acc[rr][j] = ninf2;

    const h2* xpl = &xs[(wv * 4) * XPLANE + (2 * prg) * XROW];
    const h2* wql = &ws[oL * WSTRIDE + (wv * 4) * WSLOT];

    Tile t0, t1, t2, t3;
    load_tile(t0, xpl + 0 * XPLANE, wql + 0 * WSLOT);
    load_tile(t1, xpl + 1 * XPLANE, wql + 1 * WSLOT);
    compute_tile(t0, acc);
    load_tile(t2, xpl + 2 * XPLANE, wql + 2 * WSLOT);
    compute_tile(t1, acc);
    load_tile(t3, xpl + 3 * XPLANE, wql + 3 * WSLOT);
    compute_tile(t2, acc);
    compute_tile(t3, acc);

    __syncthreads();
    if (wv != 0) {
        h2* dst = &ws[(wv - 1) * 1024 + lane * 16];
        float4 p0, p1, p2, p3;
        p0.x = asF(acc[0][0]); p0.y = asF(acc[0][1]); p0.z = asF(acc[0][2]); p0.w = asF(acc[0][3]);
        p1.x = asF(acc[0][4]); p1.y = asF(acc[0][5]); p1.z = asF(acc[0][6]); p1.w = asF(acc[0][7]);
        p2.x = asF(acc[1][0]); p2.y = asF(acc[1][1]); p2.z = asF(acc[1][2]); p2.w = asF(acc[1][3]);
        p3.x = asF(acc[1][4]); p3.y = asF(acc[1][5]); p3.z = asF(acc[1][6]); p3.w = asF(acc[1][7]);
        ((float4*)dst)[0] = p0; ((float4*)dst)[1] = p1;
        ((float4*)dst)[2] = p2; ((float4*)dst)[3] = p3;
    }
    __syncthreads();
    if (wv == 0) {
        #pragma unroll
        for (int r = 0; r < 3; ++r) {
            const h2* src = &ws[r * 1024 + lane * 16];
            #pragma unroll
            for (int half = 0; half < 2; ++half) {
                float4 pa = ((const float4*)src)[half * 2];
                float4 pb = ((const float4*)src)[half * 2 + 1];
                acc[half][0] = h2max(acc[half][0], asH2(pa.x));
                acc[half][1] = h2max(acc[half][1], asH2(pa.y));
                acc[half][2] = h2max(acc[half][2], asH2(pa.z));
                acc[half][3] = h2max(acc[half][3], asH2(pa.w));
                acc[half][4] = h2max(acc[half][4], asH2(pb.x));
                acc[half][5] = h2max(acc[half][5], asH2(pb.y));
                acc[half][6] = h2max(acc[half][6], asH2(pb.z));
                acc[half][7] = h2max(acc[half][7], asH2(pb.w));
            }
        }
        float* op = out + (((size_t)n * O_OUT + o) * HIMG + (ti0 + 2 * prg)) * WIMG + tj0;
        #pragma unroll
        for (int rr = 0; rr < 2; ++rr) {
            float4 v0, v1;
            v0.x = (float)(acc[rr][0].x > acc[rr][0].y ? acc[rr][0].x : acc[rr][0].y);
            v0.y = (float)(acc[rr][1].x > acc[rr][1].y ? acc[rr][1].x : acc[rr][1].y);
            v0.z = (float)(acc[rr][2].x > acc[rr][2].y ? acc[rr][2].x : acc[rr][2].y);
            v0.w = (float)(acc[rr][3].x > acc[rr][3].y ? acc[rr][3].x : acc[rr][3].y);
            v1.x = (float)(acc[rr][4].x > acc[rr][4].y ? acc[rr][4].x : acc[rr][4].y);
            v1.y = (float)(acc[rr][5].x > acc[rr][5].y ? acc[rr][5].x : acc[rr][5].y);
            v1.z = (float)(acc[rr][6].x > acc[rr][6].y ? acc[rr][6].x : acc[rr][6].y);
            v1.w = (float)(acc[rr][7].x > acc[rr][7].y ? acc[rr][7].x : acc[rr][7].y);
            *(float4*)(op + rr * WIMG)     = v0;
            *(float4*)(op + rr * WIMG + 4) = v1;
        }
    }
}

extern "C" void kernel_launch(void* const* d_in, const int* in_sizes, int n_in,
                              void* d_out, int out_size, void* d_ws, size_t ws_size,
                              hipStream_t stream) {
    const float* x    = (const float*)d_in[0];
    const float* kern = (const float*)d_in[1];
    float* out        = (float*)d_out;
    h2* wp            = (h2*)d_ws;                              // 24576 B
    h2* xt            = (h2*)((char*)d_ws + NW * 4);            // 12.04 MB

    const size_t need = (size_t)NW * 4 + (size_t)NXT * 4;
    const bool tiled = ws_size >= need;

    prep_weights<<<dim3((NW + 255) / 256), dim3(256), 0, stream>>>(kern, wp);
    dim3 grid(NT, NT, 8 * 2);                                   // (14, 14, 16)
    if (tiled) {
        pack_x<<<dim3((NXT + 255) / 256), dim3(256), 0, stream>>>(x, xt);
        // within-probe A/B/C on the occupancy cap; identical outputs
        semiconv_tpl<4, true><<<grid, dim3(256), 0, stream>>>(x, xt, wp, out);
        semiconv_tpl<6, true><<<grid, dim3(256), 0, stream>>>(x, xt, wp, out);
        semiconv_tpl<8, true><<<grid, dim3(256), 0, stream>>>(x, xt, wp, out);
    } else {
        semiconv_tpl<4, false><<<grid, dim3(256), 0, stream>>>(x, xt, wp, out);
    }
}

// Round 17
// 54.110 us; speedup vs baseline: 5.3321x; 5.3321x over previous
//
#include <hip/hip_runtime.h>
#include <math.h>

#define C_IN  32
#define O_OUT 32
#define HIMG  112
#define WIMG  112
#define HW    (HIMG * WIMG)
#define TS    8            // spatial tile 8x8
#define NT    14           // tiles per image dim
#define NCP   16           // c-pairs (2 channels per f16x2 reg)
#define XROW  12           // h2 per halo row (10 used) -> rows 16B-aligned
#define XPLANE (10 * XROW) // 120 h2 per c-pair plane
#define XTILE (NCP * XPLANE)          // 1920 h2 = 7680 B per (n,ti,tj)
#define NXT   (8 * NT * NT * XTILE)   // 12,042,240 B
#define WSLOT 12           // h2 per (o,cp) slot (9 used) -> 48B, b128-aligned
#define WSTRIDE 196        // h2 per o in ws (192 used +4 -> bank spread)
#define OBLK  16           // o per block (o-split 2)
#define NW    (O_OUT * NCP * WSLOT)   // 24576 B global scratch

typedef _Float16 h2 __attribute__((ext_vector_type(2)));

// R13 A/B: __builtin_elementwise_min/max scalarizes on gfx950 (ROCm 7.2);
// force v_pk_min/max_f16 via asm (~15% end-to-end).
static __device__ __forceinline__ h2 h2min(h2 a, h2 b) {
    h2 r; asm("v_pk_min_f16 %0, %1, %2" : "=v"(r) : "v"(a), "v"(b)); return r;
}
static __device__ __forceinline__ h2 h2max(h2 a, h2 b) {
    h2 r; asm("v_pk_max_f16 %0, %1, %2" : "=v"(r) : "v"(a), "v"(b)); return r;
}

static __device__ __forceinline__ h2 asH2(float f) {
    union { float f; h2 h; } u; u.f = f; return u.h;
}
static __device__ __forceinline__ float asF(h2 h) {
    union { h2 h; float f; } u; u.h = h; return u.f;
}

__global__ void prep_weights(const float* __restrict__ kern, h2* __restrict__ wp)
{
    int idx = blockIdx.x * 256 + threadIdx.x;     // 6144 total
    if (idx >= NW) return;
    int k  = idx % WSLOT;
    int cp = (idx / WSLOT) & (NCP - 1);
    int o  = idx / (WSLOT * NCP);
    float a = -INFINITY, b = -INFINITY;
    if (k < 9) {
        a = kern[(o * C_IN + 2 * cp    ) * 9 + k];
        b = kern[(o * C_IN + 2 * cp + 1) * 9 + k];
    }
    h2 v; v.x = (_Float16)a; v.y = (_Float16)b;
    wp[idx] = v;
}

// Pre-tile x: xt[n][ti][tj][cp][r(10)][col(12)] f16x2, halo + -inf baked in.
__global__ void pack_x(const float* __restrict__ x, h2* __restrict__ xt)
{
    int idx = blockIdx.x * 256 + threadIdx.x;
    if (idx >= NXT) return;
    int col = idx % XROW;
    int r   = (idx / XROW) % 10;
    int cp  = (idx / XPLANE) & (NCP - 1);
    int tj  = (idx / XTILE) % NT;
    int ti  = (idx / (XTILE * NT)) % NT;
    int n   = idx / (XTILE * NT * NT);
    int gi  = ti * TS + r - 1;
    int gj  = tj * TS + col - 1;
    float a = -INFINITY, b = -INFINITY;
    if (col < 10 && (unsigned)gi < (unsigned)HIMG && (unsigned)gj < (unsigned)WIMG) {
        const float* p = x + ((size_t)(n * C_IN + 2 * cp) * HIMG + gi) * WIMG + gj;
        a = p[0];
        b = p[HW];
    }
    h2 v; v.x = (_Float16)a; v.y = (_Float16)b;
    xt[idx] = v;
}

struct Tile {
    h2 xr[4][10];
    h2 w[9];
};

static __device__ __forceinline__ void load_tile(Tile& t, const h2* __restrict__ xp,
                                                 const h2* __restrict__ wq)
{
    #pragma unroll
    for (int q = 0; q < 4; ++q) {
        const h2* rp = xp + q * XROW;
        float4 a = *(const float4*)rp;         // ds_read_b128
        float4 b = *(const float4*)(rp + 4);   // ds_read_b128
        float2 c = *(const float2*)(rp + 8);   // ds_read_b64
        t.xr[q][0] = asH2(a.x); t.xr[q][1] = asH2(a.y);
        t.xr[q][2] = asH2(a.z); t.xr[q][3] = asH2(a.w);
        t.xr[q][4] = asH2(b.x); t.xr[q][5] = asH2(b.y);
        t.xr[q][6] = asH2(b.z); t.xr[q][7] = asH2(b.w);
        t.xr[q][8] = asH2(c.x); t.xr[q][9] = asH2(c.y);
    }
    float4 wa = *(const float4*)wq;
    float4 wb = *(const float4*)(wq + 4);
    float  wc = *(const float*)(wq + 8);
    t.w[0] = asH2(wa.x); t.w[1] = asH2(wa.y); t.w[2] = asH2(wa.z); t.w[3] = asH2(wa.w);
    t.w[4] = asH2(wb.x); t.w[5] = asH2(wb.y); t.w[6] = asH2(wb.z); t.w[7] = asH2(wb.w);
    t.w[8] = asH2(wc);
}

static __device__ __forceinline__ void compute_tile(const Tile& t, h2 acc[2][8])
{
    #pragma unroll
    for (int rr = 0; rr < 2; ++rr) {
        #pragma unroll
        for (int j = 0; j < 8; ++j) {
            h2 t0 = h2min(t.xr[rr    ][j    ], t.w[0]);
            h2 t1 = h2min(t.xr[rr    ][j + 1], t.w[1]);
            h2 t2 = h2min(t.xr[rr    ][j + 2], t.w[2]);
            h2 t3 = h2min(t.xr[rr + 1][j    ], t.w[3]);
            h2 t4 = h2min(t.xr[rr + 1][j + 1], t.w[4]);
            h2 t5 = h2min(t.xr[rr + 1][j + 2], t.w[5]);
            h2 t6 = h2min(t.xr[rr + 2][j    ], t.w[6]);
            h2 t7 = h2min(t.xr[rr + 2][j + 1], t.w[7]);
            h2 t8 = h2min(t.xr[rr + 2][j + 2], t.w[8]);
            h2 r0 = h2max(h2max(t0, t1), t2);
            h2 r1 = h2max(h2max(t3, t4), t5);
            h2 r2 = h2max(h2max(t6, t7), t8);
            acc[rr][j] = h2max(acc[rr][j], h2max(h2max(r0, r1), r2));
        }
    }
}

// Tropical (max-min) 3x3 conv, packed f16 (abs err 1.6e-2 << 7.6e-2 threshold).
// R16 A/B/C verdict: __launch_bounds__(256,6) (VGPR cap 85 >= the 64 live) is
// ~1.9x over (256,4); (256,8) spills to scratch (VGPR 32, 800MB traffic).
template<bool TILED>
__global__ __launch_bounds__(256, 6) void semiconv_tpl(
    const float* __restrict__ x, const h2* __restrict__ xt,
    const h2* __restrict__ wp, float* __restrict__ out)
{
    __shared__ h2 xs[NCP * XPLANE];      // 7680 B
    __shared__ h2 ws[OBLK * WSTRIDE];    // 12544 B (total 20224 B)

    const int tid = threadIdx.x;
    const int tj0 = blockIdx.x * TS;
    const int ti0 = blockIdx.y * TS;
    const int n   = blockIdx.z >> 1;
    const int o0  = (blockIdx.z & 1) * OBLK;

    #pragma unroll
    for (int i = 0; i < 3; ++i) {
        int chunk = i * 256 + tid;
        int oL    = chunk / 48;
        int rem   = chunk - oL * 48;
        float4 v  = *(const float4*)&wp[(size_t)((o0 + oL) * 48 + rem) * 4];
        *(float4*)&ws[oL * WSTRIDE + rem * 4] = v;
    }
    if constexpr (TILED) {
        const float4* xtp = (const float4*)(xt
            + (size_t)((n * NT + blockIdx.y) * NT + blockIdx.x) * XTILE);
        float4* xsp = (float4*)xs;
        xsp[tid] = xtp[tid];
        if (tid < 480 - 256) xsp[256 + tid] = xtp[256 + tid];
    } else {
        const float* xn = x + (size_t)n * (C_IN * HW);
        #pragma unroll 1
        for (int idx = tid; idx < NCP * XPLANE; idx += 256) {
            int cp  = idx / XPLANE;
            int rem = idx - cp * XPLANE;
            int r   = rem / XROW;
            int col = rem - r * XROW;
            int gi = ti0 - 1 + r, gj = tj0 - 1 + col;
            float a = -INFINITY, b = -INFINITY;
            if (col < 10 && (unsigned)gi < (unsigned)HIMG && (unsigned)gj < (unsigned)WIMG) {
                const float* p = xn + (size_t)(2 * cp) * HW + gi * WIMG + gj;
                a = p[0];
                b = p[HW];
            }
            h2 v; v.x = (_Float16)a; v.y = (_Float16)b;
            xs[idx] = v;
        }
    }
    __syncthreads();

    const int lane = tid & 63;
    const int wv   = tid >> 6;               // cp-quarter, 0..3
    const int oL   = lane & 15;              // o within block, 0..15
    const int prg  = lane >> 4;              // row-pair group, 0..3
    const int o    = o0 + oL;

    h2 ninf2; ninf2.x = (_Float16)(-INFINITY); ninf2.y = (_Float16)(-INFINITY);
    h2 acc[2][8];
    #pragma unroll
    for (int rr = 0; rr < 2; ++rr)
        #pragma unroll
        for (int j = 0; j < 8; ++j) acc[rr][j] = ninf2;

    const h2* xpl = &xs[(wv * 4) * XPLANE + (2 * prg) * XROW];
    const h2* wql = &ws[oL * WSTRIDE + (wv * 4) * WSLOT];

    Tile t0, t1, t2, t3;
    load_tile(t0, xpl + 0 * XPLANE, wql + 0 * WSLOT);
    load_tile(t1, xpl + 1 * XPLANE, wql + 1 * WSLOT);
    compute_tile(t0, acc);
    load_tile(t2, xpl + 2 * XPLANE, wql + 2 * WSLOT);
    compute_tile(t1, acc);
    load_tile(t3, xpl + 3 * XPLANE, wql + 3 * WSLOT);
    compute_tile(t2, acc);
    compute_tile(t3, acc);

    __syncthreads();
    if (wv != 0) {
        h2* dst = &ws[(wv - 1) * 1024 + lane * 16];
        float4 p0, p1, p2, p3;
        p0.x = asF(acc[0][0]); p0.y = asF(acc[0][1]); p0.z = asF(acc[0][2]); p0.w = asF(acc[0][3]);
        p1.x = asF(acc[0][4]); p1.y = asF(acc[0][5]); p1.z = asF(acc[0][6]); p1.w = asF(acc[0][7]);
        p2.x = asF(acc[1][0]); p2.y = asF(acc[1][1]); p2.z = asF(acc[1][2]); p2.w = asF(acc[1][3]);
        p3.x = asF(acc[1][4]); p3.y = asF(acc[1][5]); p3.z = asF(acc[1][6]); p3.w = asF(acc[1][7]);
        ((float4*)dst)[0] = p0; ((float4*)dst)[1] = p1;
        ((float4*)dst)[2] = p2; ((float4*)dst)[3] = p3;
    }
    __syncthreads();
    if (wv == 0) {
        #pragma unroll
        for (int r = 0; r < 3; ++r) {
            const h2* src = &ws[r * 1024 + lane * 16];
            #pragma unroll
            for (int half = 0; half < 2; ++half) {
                float4 pa = ((const float4*)src)[half * 2];
                float4 pb = ((const float4*)src)[half * 2 + 1];
                acc[half][0] = h2max(acc[half][0], asH2(pa.x));
                acc[half][1] = h2max(acc[half][1], asH2(pa.y));
                acc[half][2] = h2max(acc[half][2], asH2(pa.z));
                acc[half][3] = h2max(acc[half][3], asH2(pa.w));
                acc[half][4] = h2max(acc[half][4], asH2(pb.x));
                acc[half][5] = h2max(acc[half][5], asH2(pb.y));
                acc[half][6] = h2max(acc[half][6], asH2(pb.z));
                acc[half][7] = h2max(acc[half][7], asH2(pb.w));
            }
        }
        float* op = out + (((size_t)n * O_OUT + o) * HIMG + (ti0 + 2 * prg)) * WIMG + tj0;
        #pragma unroll
        for (int rr = 0; rr < 2; ++rr) {
            float4 v0, v1;
            v0.x = (float)(acc[rr][0].x > acc[rr][0].y ? acc[rr][0].x : acc[rr][0].y);
            v0.y = (float)(acc[rr][1].x > acc[rr][1].y ? acc[rr][1].x : acc[rr][1].y);
            v0.z = (float)(acc[rr][2].x > acc[rr][2].y ? acc[rr][2].x : acc[rr][2].y);
            v0.w = (float)(acc[rr][3].x > acc[rr][3].y ? acc[rr][3].x : acc[rr][3].y);
            v1.x = (float)(acc[rr][4].x > acc[rr][4].y ? acc[rr][4].x : acc[rr][4].y);
            v1.y = (float)(acc[rr][5].x > acc[rr][5].y ? acc[rr][5].x : acc[rr][5].y);
            v1.z = (float)(acc[rr][6].x > acc[rr][6].y ? acc[rr][6].x : acc[rr][6].y);
            v1.w = (float)(acc[rr][7].x > acc[rr][7].y ? acc[rr][7].x : acc[rr][7].y);
            *(float4*)(op + rr * WIMG)     = v0;
            *(float4*)(op + rr * WIMG + 4) = v1;
        }
    }
}

extern "C" void kernel_launch(void* const* d_in, const int* in_sizes, int n_in,
                              void* d_out, int out_size, void* d_ws, size_t ws_size,
                              hipStream_t stream) {
    const float* x    = (const float*)d_in[0];
    const float* kern = (const float*)d_in[1];
    float* out        = (float*)d_out;
    h2* wp            = (h2*)d_ws;                              // 24576 B
    h2* xt            = (h2*)((char*)d_ws + NW * 4);            // 12.04 MB

    const size_t need = (size_t)NW * 4 + (size_t)NXT * 4;
    const bool tiled = ws_size >= need;

    prep_weights<<<dim3((NW + 255) / 256), dim3(256), 0, stream>>>(kern, wp);
    dim3 grid(NT, NT, 8 * 2);                                   // (14, 14, 16)
    if (tiled) {
        pack_x<<<dim3((NXT + 255) / 256), dim3(256), 0, stream>>>(x, xt);
        semiconv_tpl<true ><<<grid, dim3(256), 0, stream>>>(x, xt, wp, out);
    } else {
        semiconv_tpl<false><<<grid, dim3(256), 0, stream>>>(x, xt, wp, out);
    }
}